// Round 8
// baseline (566.995 us; speedup 1.0000x reference)
//
#include <hip/hip_runtime.h>

typedef unsigned short u16;
typedef __attribute__((ext_vector_type(4))) unsigned short us4;
typedef __attribute__((ext_vector_type(4))) float f4;
typedef __attribute__((ext_vector_type(8))) short bf16x8;
typedef __attribute__((ext_vector_type(4))) float f32x4;

__device__ __forceinline__ u16 f2bf(float x) {
  unsigned u = __float_as_uint(x);
  return (u16)((u + 0x7FFFu + ((u >> 16) & 1u)) >> 16);
}
__device__ __forceinline__ float b2f(u16 s) {
  return __uint_as_float(((unsigned)s) << 16);
}
__device__ __forceinline__ float sigm(float x) { return 1.f / (1.f + __expf(-x)); }
__device__ __forceinline__ float tanhf_(float x) { return 2.f / (1.f + __expf(-2.f * x)) - 1.f; }

// ---------------------------------------------------------------------------
// Fused setup kernel (R7-verified: wave-parallel dots removed the ~110us
// latency tail that hid under the top-5 cutoff since R0).
//   bid 0..8191      : convert W/U fp32 -> bf16 (gate-major)      [BW-bound]
//   bid 8192..16383  : gather leaf tokens -> bf16                 [BW-bound]
//   bid 16384..21759 : xw + leafC dots, wave-parallel, shfl reduce
// ---------------------------------------------------------------------------
__global__ void setup_kernel(
    const float* __restrict__ tokens, const int* __restrict__ leaf_ids,
    const float* __restrict__ w0, const float* __restrict__ w1,
    const float* __restrict__ w2, const float* __restrict__ w3,
    const float* __restrict__ u0, const float* __restrict__ u1,
    const float* __restrict__ u2, const float* __restrict__ u3,
    const float* __restrict__ b0, const float* __restrict__ b1,
    const float* __restrict__ b2, const float* __restrict__ b3,
    const float* __restrict__ op_emb, const float* __restrict__ h_init,
    u16* __restrict__ Wb, u16* __restrict__ Ub, u16* __restrict__ Xl,
    float* __restrict__ xw, float* __restrict__ leafC) {
  const int bid = blockIdx.x;
  if (bid < 8192) {
    int mat = bid >> 10;
    int off4 = (int)(bid & 1023) * 256 + threadIdx.x;
    const float* src; u16* dst;
    switch (mat) {
      case 0: src = w0; dst = Wb; break;
      case 1: src = w1; dst = Wb + 1048576; break;
      case 2: src = w2; dst = Wb + 2097152; break;
      case 3: src = w3; dst = Wb + 3145728; break;
      case 4: src = u0; dst = Ub; break;
      case 5: src = u1; dst = Ub + 1048576; break;
      case 6: src = u2; dst = Ub + 2097152; break;
      default: src = u3; dst = Ub + 3145728; break;
    }
    f4 v = ((const f4*)src)[off4];
    us4 o = {f2bf(v[0]), f2bf(v[1]), f2bf(v[2]), f2bf(v[3])};
    ((us4*)dst)[off4] = o;
  } else if (bid < 16384) {
    int n = bid - 8192, t = threadIdx.x;
    int tok = leaf_ids[n];
    f4 v = ((const f4*)(tokens + (size_t)tok * 1024))[t];
    us4 o = {f2bf(v[0]), f2bf(v[1]), f2bf(v[2]), f2bf(v[3])};
    ((us4*)(Xl + (size_t)n * 1024))[t] = o;
  } else {
    const int wave = threadIdx.x >> 6, lane = threadIdx.x & 63;
    const int wid = (bid - 16384) * 4 + wave;   // 0..21503
    const f4* xr;
    const f4* wr;
    float bias;
    bool dual = false;
    const f4* xr2 = nullptr;
    float* dst;
    if (wid < 16384) {
      int op = wid >> 12, g = (wid >> 10) & 3, j = wid & 1023;
      const float* wsrc; const float* bs;
      switch (g) {
        case 0: wsrc = w0; bs = b0; break;
        case 1: wsrc = w1; bs = b1; break;
        case 2: wsrc = w2; bs = b2; break;
        default: wsrc = w3; bs = b3; break;
      }
      xr = (const f4*)(op_emb + (size_t)op * 1024);
      wr = (const f4*)(wsrc + (size_t)j * 1024);
      bias = bs[j];
      dst = xw + wid;
    } else {
      int id2 = wid - 16384;                    // 0..5119
      int sel = id2 >> 10, j = id2 & 1023;
      const f4* h0 = (const f4*)h_init;
      const f4* h1 = (const f4*)(h_init + 1024);
      if (sel < 3) {
        const float* usrc; const float* bs;
        switch (sel) {
          case 0: usrc = u0; bs = b0; break;
          case 1: usrc = u1; bs = b1; break;
          default: usrc = u2; bs = b2; break;
        }
        xr = h0; xr2 = h1; dual = true;
        wr = (const f4*)(usrc + (size_t)j * 1024);
        bias = bs[j];
      } else {
        xr = (sel == 3) ? h0 : h1;
        wr = (const f4*)(u3 + (size_t)j * 1024);
        bias = b3[j];
      }
      dst = leafC + id2;
    }
    float s = 0.f;
#pragma unroll
    for (int i = 0; i < 4; ++i) {
      int k = lane + 64 * i;
      f4 a = xr[k];
      if (dual) {
        f4 a2 = xr2[k];
        a[0] += a2[0]; a[1] += a2[1]; a[2] += a2[2]; a[3] += a2[3];
      }
      f4 b = wr[k];
      s += a[0] * b[0] + a[1] * b[1] + a[2] * b[2] + a[3] * b[3];
    }
#pragma unroll
    for (int off = 32; off > 0; off >>= 1) s += __shfl_xor(s, off);
    if (lane == 0) *dst = s + bias;
  }
}

// ---------------------------------------------------------------------------
// Main fused GEMM + TreeLSTM node kernel (R0 loop structure — verified best:
// mid-chunk B prefetch, dbuf LDS A staging via global_load_lds w=16 with
// XOR-granule swizzle).
// R8 experiment (clean resolution of R6's masked A/B): epilogue passes
// doubled (RPP=32 for all NRT) so the epilogue LDS buffer (4*32*68 u16 =
// 8.7KB) no longer exceeds the 32KB staging dbuf. <8,2> LDS: 34816 ->
// 32768 B => LDS co-residency cap 4 -> 5 blocks/CU. K-loop untouched.
// Decision rule: occupancy+dur improve => LDS was binding; unchanged =>
// big GEMMs are ramp/latency-bound, stop occupancy tuning.
// ---------------------------------------------------------------------------
template <int NRT, int NCT>
__global__ __launch_bounds__(256, (NRT == 8 ? 2 : 3)) void tree_gemm(
    const u16* __restrict__ A, const u16* __restrict__ Wm,
    const float* __restrict__ consts,   // leafC[5][1024] or xw[4][4][1024]
    const int* __restrict__ ops,        // nullptr for leaf
    const float* __restrict__ c_in,     // c_init[2][1024] or child c
    float* __restrict__ c_out, u16* __restrict__ h_out,
    int nrows, int m_parents, int is_leaf, float* __restrict__ out_root) {
  constexpr int ROWS = NRT * 16;
  constexpr int COLS = NCT * 16;
  constexpr int S = 64 / NCT;
  constexpr int LOG2S = (NCT == 2 ? 5 : 4);
  constexpr int NST = NRT / 2;
  constexpr int DBUF = NRT * 2048;
  constexpr int PASSES = (NRT == 8 ? 4 : (NRT == 4 ? 2 : 1));
  constexpr int RPP = ROWS / PASSES;        // = 32 for all configs
  constexpr int FPP = RPP / 16;             // = 2
  constexpr int SMEM_U16 =
      (4 * RPP * 68 > NRT * 2048 ? 4 * RPP * 68 : NRT * 2048);
  __shared__ __align__(16) u16 smem[SMEM_U16];
  char* smem_c = (char*)smem;

  const int tid = threadIdx.x;
  const int wave = tid >> 6;
  const int lane = tid & 63;
  const int stripe = blockIdx.x & (S - 1);
  const int rowblk = blockIdx.x >> LOG2S;
  const int r0 = rowblk * ROWS;
  const int j0 = stripe * COLS;
  const int ln15 = lane & 15, quad = lane >> 4;
  const int sub = lane >> 3, gsel = lane & 7;

  const char* pAsrc[NST];
  unsigned a_dst[NST];
#pragma unroll
  for (int i = 0; i < NST; ++i) {
    int slot = (wave * NST + i) * 8 + sub;
    int row = r0 + slot; if (row >= nrows) row = nrows - 1;
    pAsrc[i] = (const char*)(A + (size_t)row * 1024 + (unsigned)((gsel ^ sub) * 8));
    a_dst[i] = (unsigned)((wave * NST + i) * 1024 + lane * 16);
  }
  const char* pB[NCT];
#pragma unroll
  for (int f = 0; f < NCT; ++f)
    pB[f] = (const char*)(Wm + (size_t)(wave * 1024 + j0 + f * 16 + ln15) * 1024 + quad * 8);

  unsigned a_base[2];
#pragma unroll
  for (int ks = 0; ks < 2; ++ks)
    a_base[ks] = (unsigned)(ln15 * 128 + (((ks * 4 + quad) ^ (ln15 & 7)) * 16));

  f32x4 acc[NRT][NCT];
#pragma unroll
  for (int t = 0; t < NRT; ++t)
#pragma unroll
    for (int f = 0; f < NCT; ++f) acc[t][f] = (f32x4){0.f, 0.f, 0.f, 0.f};

#pragma unroll
  for (int i = 0; i < NST; ++i)
    __builtin_amdgcn_global_load_lds(
        (const __attribute__((address_space(1))) void*)(pAsrc[i]),
        (__attribute__((address_space(3))) void*)(smem_c + a_dst[i]), 16, 0, 0);
  bf16x8 bcur[2][NCT], bnxt[2][NCT];
#pragma unroll
  for (int ks = 0; ks < 2; ++ks)
#pragma unroll
    for (int f = 0; f < NCT; ++f)
      bcur[ks][f] = *(const bf16x8*)(pB[f] + ks * 64);

#pragma unroll
  for (int ch = 0; ch < 16; ++ch) {
    __syncthreads();
    if (ch < 15) {
#pragma unroll
      for (int i = 0; i < NST; ++i)
        __builtin_amdgcn_global_load_lds(
            (const __attribute__((address_space(1))) void*)(pAsrc[i] + (ch + 1) * 128),
            (__attribute__((address_space(3))) void*)(smem_c + ((ch + 1) & 1) * DBUF + a_dst[i]),
            16, 0, 0);
    }
    const unsigned cb = (unsigned)((ch & 1) * DBUF);
    {
      bf16x8 af[NRT];
#pragma unroll
      for (int t = 0; t < NRT; ++t)
        af[t] = *(const bf16x8*)(smem_c + cb + a_base[0] + t * 2048);
#pragma unroll
      for (int t = 0; t < NRT; ++t)
#pragma unroll
        for (int f = 0; f < NCT; ++f)
          acc[t][f] = __builtin_amdgcn_mfma_f32_16x16x32_bf16(af[t], bcur[0][f],
                                                              acc[t][f], 0, 0, 0);
    }
    if (ch < 15) {
#pragma unroll
      for (int ks = 0; ks < 2; ++ks)
#pragma unroll
        for (int f = 0; f < NCT; ++f)
          bnxt[ks][f] = *(const bf16x8*)(pB[f] + (ch + 1) * 128 + ks * 64);
    }
    {
      bf16x8 af[NRT];
#pragma unroll
      for (int t = 0; t < NRT; ++t)
        af[t] = *(const bf16x8*)(smem_c + cb + a_base[1] + t * 2048);
#pragma unroll
      for (int t = 0; t < NRT; ++t)
#pragma unroll
        for (int f = 0; f < NCT; ++f)
          acc[t][f] = __builtin_amdgcn_mfma_f32_16x16x32_bf16(af[t], bcur[1][f],
                                                              acc[t][f], 0, 0, 0);
    }
#pragma unroll
    for (int ks = 0; ks < 2; ++ks)
#pragma unroll
      for (int f = 0; f < NCT; ++f) bcur[ks][f] = bnxt[ks][f];
  }

#pragma unroll
  for (int pass = 0; pass < PASSES; ++pass) {
    __syncthreads();
#pragma unroll
    for (int tt = 0; tt < FPP; ++tt) {
      int t = pass * FPP + tt;
#pragma unroll
      for (int f = 0; f < NCT; ++f)
#pragma unroll
        for (int k = 0; k < 4; ++k) {
          int row = tt * 16 + quad * 4 + k;
          int col = f * 16 + ln15;
          smem[(wave * RPP + row) * 68 + col] = f2bf(acc[t][f][k]);
        }
    }
    __syncthreads();
    const int rbase = r0 + pass * RPP;

    if (is_leaf) {
      for (int e = tid; e < RPP * COLS; e += 256) {
        int r = e / COLS, j = e % COLS;
        int col = j0 + j, n = rbase + r;
        float p0 = b2f(smem[(0 * RPP + r) * 68 + j]);
        float p1 = b2f(smem[(1 * RPP + r) * 68 + j]);
        float p2 = b2f(smem[(2 * RPP + r) * 68 + j]);
        float p3 = b2f(smem[(3 * RPP + r) * 68 + j]);
        float i_ = sigm(p0 + consts[col]);
        float o_ = sigm(p1 + consts[1024 + col]);
        float u_ = tanhf_(p2 + consts[2048 + col]);
        float f0 = sigm(p3 + consts[3072 + col]);
        float f1 = sigm(p3 + consts[4096 + col]);
        float c = i_ * u_ + f0 * c_in[col] + f1 * c_in[1024 + col];
        float h = o_ * tanhf_(c);
        c_out[(size_t)n * 1024 + col] = c;
        h_out[(size_t)n * 1024 + col] = f2bf(h);
      }
    } else {
      for (int e = tid; e < (RPP / 2) * COLS; e += 256) {
        int p = e / COLS, j = e % COLS;
        int np = (rbase >> 1) + p;
        if (np >= m_parents) break;
        int col = j0 + j;
        int op = ops[np];
        const float* xwop = consts + ((unsigned)(op * 4) << 10);
        float p0a = b2f(smem[(0 * RPP + 2 * p) * 68 + j]), p0b = b2f(smem[(0 * RPP + 2 * p + 1) * 68 + j]);
        float p1a = b2f(smem[(1 * RPP + 2 * p) * 68 + j]), p1b = b2f(smem[(1 * RPP + 2 * p + 1) * 68 + j]);
        float p2a = b2f(smem[(2 * RPP + 2 * p) * 68 + j]), p2b = b2f(smem[(2 * RPP + 2 * p + 1) * 68 + j]);
        float p3a = b2f(smem[(3 * RPP + 2 * p) * 68 + j]), p3b = b2f(smem[(3 * RPP + 2 * p + 1) * 68 + j]);
        float i_ = sigm(p0a + p0b + xwop[col]);
        float o_ = sigm(p1a + p1b + xwop[1024 + col]);
        float u_ = tanhf_(p2a + p2b + xwop[2048 + col]);
        float f0 = sigm(p3a + xwop[3072 + col]);
        float f1 = sigm(p3b + xwop[3072 + col]);
        float c = i_ * u_ + f0 * c_in[(size_t)(rbase + 2 * p) * 1024 + col]
                          + f1 * c_in[(size_t)(rbase + 2 * p + 1) * 1024 + col];
        float h = o_ * tanhf_(c);
        if (m_parents == 1) {
          out_root[col] = c;
          out_root[1024 + col] = h;
        } else {
          c_out[(size_t)np * 1024 + col] = c;
          h_out[(size_t)np * 1024 + col] = f2bf(h);
        }
      }
    }
  }
}

// ---------------------------------------------------------------------------
extern "C" void kernel_launch(void* const* d_in, const int* in_sizes, int n_in,
                              void* d_out, int out_size, void* d_ws, size_t ws_size,
                              hipStream_t stream) {
  const float* tokens = (const float*)d_in[0];
  const int* leaf_ids = (const int*)d_in[1];
  const int* op_ids = (const int*)d_in[2];
  const float* W0 = (const float*)d_in[3];
  const float* W1 = (const float*)d_in[4];
  const float* W2 = (const float*)d_in[5];
  const float* W3 = (const float*)d_in[6];
  const float* U0 = (const float*)d_in[7];
  const float* U1 = (const float*)d_in[8];
  const float* U2 = (const float*)d_in[9];
  const float* U3 = (const float*)d_in[10];
  const float* B0 = (const float*)d_in[11];
  const float* B1 = (const float*)d_in[12];
  const float* B2 = (const float*)d_in[13];
  const float* B3 = (const float*)d_in[14];
  const float* op_emb = (const float*)d_in[15];
  const float* c_init = (const float*)d_in[16];
  const float* h_init = (const float*)d_in[17];
  float* out = (float*)d_out;

  char* ws = (char*)d_ws;
  u16* Wb = (u16*)ws;
  u16* Ub = Wb + (size_t)4 * 1024 * 1024;
  u16* Xl = Ub + (size_t)4 * 1024 * 1024;
  u16* hA = Xl + (size_t)8192 * 1024;
  u16* hB = hA + (size_t)8192 * 1024;
  float* cA = (float*)(hB + (size_t)4096 * 1024);
  float* cB = cA + (size_t)8192 * 1024;
  float* xw = cB + (size_t)4096 * 1024;
  float* lc = xw + 16 * 1024;

  // fused setup: convert (8192) | gather (8192) | wave-parallel dots (5376)
  setup_kernel<<<21760, 256, 0, stream>>>(tokens, leaf_ids,
                                          W0, W1, W2, W3, U0, U1, U2, U3,
                                          B0, B1, B2, B3, op_emb, h_init,
                                          Wb, Ub, Xl, xw, lc);

  // leaves: 8192 rows -> <8,2>: 64 rowgroups x 32 stripes
  tree_gemm<8, 2><<<64 * 32, 256, 0, stream>>>(Xl, Wb, lc, nullptr, c_init,
                                               cA, hA, 8192, 0, 1, out);

  const u16* hin = hA; const float* cin = cA;
  u16* hout = hB; float* cout = cB;
  for (int l = 12; l >= 0; --l) {
    int m = 1 << l;
    int nrows = 2 * m;
    if (nrows >= 2048) {
      tree_gemm<8, 2><<<(nrows / 128) * 32, 256, 0, stream>>>(
          hin, Ub, xw, op_ids + (m - 1), cin, cout, hout, nrows, m, 0, out);
    } else if (nrows >= 1024) {
      tree_gemm<4, 2><<<(nrows / 64) * 32, 256, 0, stream>>>(
          hin, Ub, xw, op_ids + (m - 1), cin, cout, hout, nrows, m, 0, out);
    } else {
      int rg = nrows / 32; if (rg < 1) rg = 1;
      tree_gemm<2, 2><<<rg * 32, 256, 0, stream>>>(
          hin, Ub, xw, op_ids + (m - 1), cin, cout, hout, nrows, m, 0, out);
    }
    const u16* th = hin; hin = hout; hout = (u16*)th;
    const float* tc = cin; cin = cout; cout = (float*)tc;
  }
}

// Round 9
// 551.130 us; speedup vs baseline: 1.0288x; 1.0288x over previous
//
#include <hip/hip_runtime.h>

typedef unsigned short u16;
typedef __attribute__((ext_vector_type(4))) unsigned short us4;
typedef __attribute__((ext_vector_type(4))) float f4;
typedef __attribute__((ext_vector_type(8))) short bf16x8;
typedef __attribute__((ext_vector_type(4))) float f32x4;

__device__ __forceinline__ u16 f2bf(float x) {
  unsigned u = __float_as_uint(x);
  return (u16)((u + 0x7FFFu + ((u >> 16) & 1u)) >> 16);
}
__device__ __forceinline__ float b2f(u16 s) {
  return __uint_as_float(((unsigned)s) << 16);
}
__device__ __forceinline__ float sigm(float x) { return 1.f / (1.f + __expf(-x)); }
__device__ __forceinline__ float tanhf_(float x) { return 2.f / (1.f + __expf(-2.f * x)) - 1.f; }

// ---------------------------------------------------------------------------
// Fused setup kernel (R7-verified).
//   bid 0..8191      : convert W/U fp32 -> bf16 (gate-major)      [BW-bound]
//   bid 8192..16383  : gather leaf tokens -> bf16                 [BW-bound]
//   bid 16384..21759 : xw + leafC dots, wave-parallel, shfl reduce
// ---------------------------------------------------------------------------
__global__ void setup_kernel(
    const float* __restrict__ tokens, const int* __restrict__ leaf_ids,
    const float* __restrict__ w0, const float* __restrict__ w1,
    const float* __restrict__ w2, const float* __restrict__ w3,
    const float* __restrict__ u0, const float* __restrict__ u1,
    const float* __restrict__ u2, const float* __restrict__ u3,
    const float* __restrict__ b0, const float* __restrict__ b1,
    const float* __restrict__ b2, const float* __restrict__ b3,
    const float* __restrict__ op_emb, const float* __restrict__ h_init,
    u16* __restrict__ Wb, u16* __restrict__ Ub, u16* __restrict__ Xl,
    float* __restrict__ xw, float* __restrict__ leafC) {
  const int bid = blockIdx.x;
  if (bid < 8192) {
    int mat = bid >> 10;
    int off4 = (int)(bid & 1023) * 256 + threadIdx.x;
    const float* src; u16* dst;
    switch (mat) {
      case 0: src = w0; dst = Wb; break;
      case 1: src = w1; dst = Wb + 1048576; break;
      case 2: src = w2; dst = Wb + 2097152; break;
      case 3: src = w3; dst = Wb + 3145728; break;
      case 4: src = u0; dst = Ub; break;
      case 5: src = u1; dst = Ub + 1048576; break;
      case 6: src = u2; dst = Ub + 2097152; break;
      default: src = u3; dst = Ub + 3145728; break;
    }
    f4 v = ((const f4*)src)[off4];
    us4 o = {f2bf(v[0]), f2bf(v[1]), f2bf(v[2]), f2bf(v[3])};
    ((us4*)dst)[off4] = o;
  } else if (bid < 16384) {
    int n = bid - 8192, t = threadIdx.x;
    int tok = leaf_ids[n];
    f4 v = ((const f4*)(tokens + (size_t)tok * 1024))[t];
    us4 o = {f2bf(v[0]), f2bf(v[1]), f2bf(v[2]), f2bf(v[3])};
    ((us4*)(Xl + (size_t)n * 1024))[t] = o;
  } else {
    const int wave = threadIdx.x >> 6, lane = threadIdx.x & 63;
    const int wid = (bid - 16384) * 4 + wave;   // 0..21503
    const f4* xr;
    const f4* wr;
    float bias;
    bool dual = false;
    const f4* xr2 = nullptr;
    float* dst;
    if (wid < 16384) {
      int op = wid >> 12, g = (wid >> 10) & 3, j = wid & 1023;
      const float* wsrc; const float* bs;
      switch (g) {
        case 0: wsrc = w0; bs = b0; break;
        case 1: wsrc = w1; bs = b1; break;
        case 2: wsrc = w2; bs = b2; break;
        default: wsrc = w3; bs = b3; break;
      }
      xr = (const f4*)(op_emb + (size_t)op * 1024);
      wr = (const f4*)(wsrc + (size_t)j * 1024);
      bias = bs[j];
      dst = xw + wid;
    } else {
      int id2 = wid - 16384;                    // 0..5119
      int sel = id2 >> 10, j = id2 & 1023;
      const f4* h0 = (const f4*)h_init;
      const f4* h1 = (const f4*)(h_init + 1024);
      if (sel < 3) {
        const float* usrc; const float* bs;
        switch (sel) {
          case 0: usrc = u0; bs = b0; break;
          case 1: usrc = u1; bs = b1; break;
          default: usrc = u2; bs = b2; break;
        }
        xr = h0; xr2 = h1; dual = true;
        wr = (const f4*)(usrc + (size_t)j * 1024);
        bias = bs[j];
      } else {
        xr = (sel == 3) ? h0 : h1;
        wr = (const f4*)(u3 + (size_t)j * 1024);
        bias = b3[j];
      }
      dst = leafC + id2;
    }
    float s = 0.f;
#pragma unroll
    for (int i = 0; i < 4; ++i) {
      int k = lane + 64 * i;
      f4 a = xr[k];
      if (dual) {
        f4 a2 = xr2[k];
        a[0] += a2[0]; a[1] += a2[1]; a[2] += a2[2]; a[3] += a2[3];
      }
      f4 b = wr[k];
      s += a[0] * b[0] + a[1] * b[1] + a[2] * b[2] + a[3] * b[3];
    }
#pragma unroll
    for (int off = 32; off > 0; off >>= 1) s += __shfl_xor(s, off);
    if (lane == 0) *dst = s + bias;
  }
}

// ---------------------------------------------------------------------------
// Main fused GEMM + TreeLSTM node kernel (R0 loop structure — verified best:
// mid-chunk B prefetch, dbuf LDS A staging via global_load_lds w=16 with
// XOR-granule swizzle). R8: RPP=32 epilogue (LDS 32768; perf identical to
// 34816 baseline — occupancy experiment closed NULL, keeping smaller LDS).
// ---------------------------------------------------------------------------
template <int NRT, int NCT>
__global__ __launch_bounds__(256, (NRT == 8 ? 2 : 3)) void tree_gemm(
    const u16* __restrict__ A, const u16* __restrict__ Wm,
    const float* __restrict__ consts,   // leafC[5][1024] or xw[4][4][1024]
    const int* __restrict__ ops,        // nullptr for leaf
    const float* __restrict__ c_in,     // c_init[2][1024] or child c
    float* __restrict__ c_out, u16* __restrict__ h_out,
    int nrows, int m_parents, int is_leaf, float* __restrict__ out_root) {
  constexpr int ROWS = NRT * 16;
  constexpr int COLS = NCT * 16;
  constexpr int S = 64 / NCT;
  constexpr int LOG2S = (NCT == 2 ? 5 : 4);
  constexpr int NST = NRT / 2;
  constexpr int DBUF = NRT * 2048;
  constexpr int PASSES = (NRT == 8 ? 4 : (NRT == 4 ? 2 : 1));
  constexpr int RPP = ROWS / PASSES;        // = 32 for all configs
  constexpr int FPP = RPP / 16;             // = 2
  constexpr int SMEM_U16 =
      (4 * RPP * 68 > NRT * 2048 ? 4 * RPP * 68 : NRT * 2048);
  __shared__ __align__(16) u16 smem[SMEM_U16];
  char* smem_c = (char*)smem;

  const int tid = threadIdx.x;
  const int wave = tid >> 6;
  const int lane = tid & 63;
  const int stripe = blockIdx.x & (S - 1);
  const int rowblk = blockIdx.x >> LOG2S;
  const int r0 = rowblk * ROWS;
  const int j0 = stripe * COLS;
  const int ln15 = lane & 15, quad = lane >> 4;
  const int sub = lane >> 3, gsel = lane & 7;

  const char* pAsrc[NST];
  unsigned a_dst[NST];
#pragma unroll
  for (int i = 0; i < NST; ++i) {
    int slot = (wave * NST + i) * 8 + sub;
    int row = r0 + slot; if (row >= nrows) row = nrows - 1;
    pAsrc[i] = (const char*)(A + (size_t)row * 1024 + (unsigned)((gsel ^ sub) * 8));
    a_dst[i] = (unsigned)((wave * NST + i) * 1024 + lane * 16);
  }
  const char* pB[NCT];
#pragma unroll
  for (int f = 0; f < NCT; ++f)
    pB[f] = (const char*)(Wm + (size_t)(wave * 1024 + j0 + f * 16 + ln15) * 1024 + quad * 8);

  unsigned a_base[2];
#pragma unroll
  for (int ks = 0; ks < 2; ++ks)
    a_base[ks] = (unsigned)(ln15 * 128 + (((ks * 4 + quad) ^ (ln15 & 7)) * 16));

  f32x4 acc[NRT][NCT];
#pragma unroll
  for (int t = 0; t < NRT; ++t)
#pragma unroll
    for (int f = 0; f < NCT; ++f) acc[t][f] = (f32x4){0.f, 0.f, 0.f, 0.f};

#pragma unroll
  for (int i = 0; i < NST; ++i)
    __builtin_amdgcn_global_load_lds(
        (const __attribute__((address_space(1))) void*)(pAsrc[i]),
        (__attribute__((address_space(3))) void*)(smem_c + a_dst[i]), 16, 0, 0);
  bf16x8 bcur[2][NCT], bnxt[2][NCT];
#pragma unroll
  for (int ks = 0; ks < 2; ++ks)
#pragma unroll
    for (int f = 0; f < NCT; ++f)
      bcur[ks][f] = *(const bf16x8*)(pB[f] + ks * 64);

#pragma unroll
  for (int ch = 0; ch < 16; ++ch) {
    __syncthreads();
    if (ch < 15) {
#pragma unroll
      for (int i = 0; i < NST; ++i)
        __builtin_amdgcn_global_load_lds(
            (const __attribute__((address_space(1))) void*)(pAsrc[i] + (ch + 1) * 128),
            (__attribute__((address_space(3))) void*)(smem_c + ((ch + 1) & 1) * DBUF + a_dst[i]),
            16, 0, 0);
    }
    const unsigned cb = (unsigned)((ch & 1) * DBUF);
    {
      bf16x8 af[NRT];
#pragma unroll
      for (int t = 0; t < NRT; ++t)
        af[t] = *(const bf16x8*)(smem_c + cb + a_base[0] + t * 2048);
#pragma unroll
      for (int t = 0; t < NRT; ++t)
#pragma unroll
        for (int f = 0; f < NCT; ++f)
          acc[t][f] = __builtin_amdgcn_mfma_f32_16x16x32_bf16(af[t], bcur[0][f],
                                                              acc[t][f], 0, 0, 0);
    }
    if (ch < 15) {
#pragma unroll
      for (int ks = 0; ks < 2; ++ks)
#pragma unroll
        for (int f = 0; f < NCT; ++f)
          bnxt[ks][f] = *(const bf16x8*)(pB[f] + (ch + 1) * 128 + ks * 64);
    }
    {
      bf16x8 af[NRT];
#pragma unroll
      for (int t = 0; t < NRT; ++t)
        af[t] = *(const bf16x8*)(smem_c + cb + a_base[1] + t * 2048);
#pragma unroll
      for (int t = 0; t < NRT; ++t)
#pragma unroll
        for (int f = 0; f < NCT; ++f)
          acc[t][f] = __builtin_amdgcn_mfma_f32_16x16x32_bf16(af[t], bcur[1][f],
                                                              acc[t][f], 0, 0, 0);
    }
#pragma unroll
    for (int ks = 0; ks < 2; ++ks)
#pragma unroll
      for (int f = 0; f < NCT; ++f) bcur[ks][f] = bnxt[ks][f];
  }

#pragma unroll
  for (int pass = 0; pass < PASSES; ++pass) {
    __syncthreads();
#pragma unroll
    for (int tt = 0; tt < FPP; ++tt) {
      int t = pass * FPP + tt;
#pragma unroll
      for (int f = 0; f < NCT; ++f)
#pragma unroll
        for (int k = 0; k < 4; ++k) {
          int row = tt * 16 + quad * 4 + k;
          int col = f * 16 + ln15;
          smem[(wave * RPP + row) * 68 + col] = f2bf(acc[t][f][k]);
        }
    }
    __syncthreads();
    const int rbase = r0 + pass * RPP;

    if (is_leaf) {
      for (int e = tid; e < RPP * COLS; e += 256) {
        int r = e / COLS, j = e % COLS;
        int col = j0 + j, n = rbase + r;
        float p0 = b2f(smem[(0 * RPP + r) * 68 + j]);
        float p1 = b2f(smem[(1 * RPP + r) * 68 + j]);
        float p2 = b2f(smem[(2 * RPP + r) * 68 + j]);
        float p3 = b2f(smem[(3 * RPP + r) * 68 + j]);
        float i_ = sigm(p0 + consts[col]);
        float o_ = sigm(p1 + consts[1024 + col]);
        float u_ = tanhf_(p2 + consts[2048 + col]);
        float f0 = sigm(p3 + consts[3072 + col]);
        float f1 = sigm(p3 + consts[4096 + col]);
        float c = i_ * u_ + f0 * c_in[col] + f1 * c_in[1024 + col];
        float h = o_ * tanhf_(c);
        c_out[(size_t)n * 1024 + col] = c;
        h_out[(size_t)n * 1024 + col] = f2bf(h);
      }
    } else {
      for (int e = tid; e < (RPP / 2) * COLS; e += 256) {
        int p = e / COLS, j = e % COLS;
        int np = (rbase >> 1) + p;
        if (np >= m_parents) break;
        int col = j0 + j;
        int op = ops[np];
        const float* xwop = consts + ((unsigned)(op * 4) << 10);
        float p0a = b2f(smem[(0 * RPP + 2 * p) * 68 + j]), p0b = b2f(smem[(0 * RPP + 2 * p + 1) * 68 + j]);
        float p1a = b2f(smem[(1 * RPP + 2 * p) * 68 + j]), p1b = b2f(smem[(1 * RPP + 2 * p + 1) * 68 + j]);
        float p2a = b2f(smem[(2 * RPP + 2 * p) * 68 + j]), p2b = b2f(smem[(2 * RPP + 2 * p + 1) * 68 + j]);
        float p3a = b2f(smem[(3 * RPP + 2 * p) * 68 + j]), p3b = b2f(smem[(3 * RPP + 2 * p + 1) * 68 + j]);
        float i_ = sigm(p0a + p0b + xwop[col]);
        float o_ = sigm(p1a + p1b + xwop[1024 + col]);
        float u_ = tanhf_(p2a + p2b + xwop[2048 + col]);
        float f0 = sigm(p3a + xwop[3072 + col]);
        float f1 = sigm(p3b + xwop[3072 + col]);
        float c = i_ * u_ + f0 * c_in[(size_t)(rbase + 2 * p) * 1024 + col]
                          + f1 * c_in[(size_t)(rbase + 2 * p + 1) * 1024 + col];
        float h = o_ * tanhf_(c);
        if (m_parents == 1) {
          out_root[col] = c;
          out_root[1024 + col] = h;
        } else {
          c_out[(size_t)np * 1024 + col] = c;
          h_out[(size_t)np * 1024 + col] = f2bf(h);
        }
      }
    }
  }
}

// ---------------------------------------------------------------------------
// Small-level kernel (nrows <= 512), R4-verified body, now ISOLATED (R4
// bundled it with the split-path regression so its own effect was never
// measured). Latency structure strictly better than tree_gemm<2,2> at tiny
// grids: all 32 rows x 1024 staged ONCE into 64KB LDS (one HBM round-trip,
// ONE barrier) -> fully-unrolled ZERO-barrier K-loop (compiler hoists the
// 128 B-loads deeply). 3 barriers total vs 18.
// ---------------------------------------------------------------------------
__global__ __launch_bounds__(256, 2) void small_gemm(
    const u16* __restrict__ A, const u16* __restrict__ Um,
    const float* __restrict__ xw, const int* __restrict__ ops,
    const float* __restrict__ c_in,
    float* __restrict__ c_out, u16* __restrict__ h_out,
    int nrows, int m_parents, float* __restrict__ out_root) {
  __shared__ __align__(16) u16 smem[32768];   // 64 KB: [ch][rowpack] layout
  char* smem_c = (char*)smem;
  const int tid = threadIdx.x;
  const int wave = tid >> 6, lane = tid & 63;
  const int stripe = blockIdx.x & 31, rowblk = blockIdx.x >> 5;
  const int r0 = rowblk * 32, j0 = stripe * 32;
  const int ln15 = lane & 15, quad = lane >> 4;
  const int sub = lane >> 3, gsel = lane & 7;

  // stage all 32 rows x 1024: 64 wave-jobs (1 KB), 16 per wave.
  // job w: ch = w>>2, rows (w&3)*8+sub, LDS [w*1024 + lane*16],
  // src granule (gsel^sub) of row's chunk ch (u16 units throughout).
#pragma unroll
  for (int i = 0; i < 16; ++i) {
    int w = wave * 16 + i;
    int ch = w >> 2;
    int row = r0 + (w & 3) * 8 + sub;
    if (row >= nrows) row = nrows - 1;
    const char* src = (const char*)(A + (size_t)row * 1024 + (unsigned)(ch * 64) + (unsigned)((gsel ^ sub) * 8));
    __builtin_amdgcn_global_load_lds(
        (const __attribute__((address_space(1))) void*)src,
        (__attribute__((address_space(3))) void*)(smem_c + w * 1024 + lane * 16), 16, 0, 0);
  }
  const char* pB[2];
#pragma unroll
  for (int f = 0; f < 2; ++f)
    pB[f] = (const char*)(Um + (size_t)(wave * 1024 + j0 + f * 16 + ln15) * 1024 + quad * 8);
  unsigned a_base[2];
#pragma unroll
  for (int ks = 0; ks < 2; ++ks)
    a_base[ks] = (unsigned)(ln15 * 128 + (((ks * 4 + quad) ^ (ln15 & 7)) * 16));

  f32x4 acc[2][2];
#pragma unroll
  for (int t = 0; t < 2; ++t)
#pragma unroll
    for (int f = 0; f < 2; ++f) acc[t][f] = (f32x4){0.f, 0.f, 0.f, 0.f};

  __syncthreads();   // staging drained; no further barriers in K-loop

#pragma unroll
  for (int ch = 0; ch < 16; ++ch) {
    bf16x8 b[2][2];
#pragma unroll
    for (int ks = 0; ks < 2; ++ks)
#pragma unroll
      for (int f = 0; f < 2; ++f)
        b[ks][f] = *(const bf16x8*)(pB[f] + ch * 128 + ks * 64);
#pragma unroll
    for (int ks = 0; ks < 2; ++ks) {
      bf16x8 af[2];
#pragma unroll
      for (int t = 0; t < 2; ++t)
        af[t] = *(const bf16x8*)(smem_c + ch * 4096 + a_base[ks] + t * 2048);
#pragma unroll
      for (int t = 0; t < 2; ++t)
#pragma unroll
        for (int f = 0; f < 2; ++f)
          acc[t][f] = __builtin_amdgcn_mfma_f32_16x16x32_bf16(af[t], b[ks][f], acc[t][f], 0, 0, 0);
    }
  }

  __syncthreads();
#pragma unroll
  for (int t = 0; t < 2; ++t)
#pragma unroll
    for (int f = 0; f < 2; ++f)
#pragma unroll
      for (int k = 0; k < 4; ++k) {
        int row = t * 16 + quad * 4 + k;
        int col = f * 16 + ln15;
        smem[(wave * 32 + row) * 68 + col] = f2bf(acc[t][f][k]);
      }
  __syncthreads();
  for (int e = tid; e < 16 * 32; e += 256) {
    int p = e >> 5, j = e & 31;
    int np = (r0 >> 1) + p;
    if (np >= m_parents) break;
    int col = j0 + j;
    int op = ops[np];
    const float* xwop = xw + ((unsigned)op << 12);
    float p0a = b2f(smem[(0 * 32 + 2 * p) * 68 + j]), p0b = b2f(smem[(0 * 32 + 2 * p + 1) * 68 + j]);
    float p1a = b2f(smem[(1 * 32 + 2 * p) * 68 + j]), p1b = b2f(smem[(1 * 32 + 2 * p + 1) * 68 + j]);
    float p2a = b2f(smem[(2 * 32 + 2 * p) * 68 + j]), p2b = b2f(smem[(2 * 32 + 2 * p + 1) * 68 + j]);
    float p3a = b2f(smem[(3 * 32 + 2 * p) * 68 + j]), p3b = b2f(smem[(3 * 32 + 2 * p + 1) * 68 + j]);
    float i_ = sigm(p0a + p0b + xwop[col]);
    float o_ = sigm(p1a + p1b + xwop[1024 + col]);
    float u_ = tanhf_(p2a + p2b + xwop[2048 + col]);
    float f0 = sigm(p3a + xwop[3072 + col]);
    float f1 = sigm(p3b + xwop[3072 + col]);
    float c = i_ * u_ + f0 * c_in[(size_t)(r0 + 2 * p) * 1024 + col]
                      + f1 * c_in[(size_t)(r0 + 2 * p + 1) * 1024 + col];
    float h = o_ * tanhf_(c);
    if (m_parents == 1) {
      out_root[col] = c;
      out_root[1024 + col] = h;
    } else {
      c_out[(size_t)np * 1024 + col] = c;
      h_out[(size_t)np * 1024 + col] = f2bf(h);
    }
  }
}

// ---------------------------------------------------------------------------
extern "C" void kernel_launch(void* const* d_in, const int* in_sizes, int n_in,
                              void* d_out, int out_size, void* d_ws, size_t ws_size,
                              hipStream_t stream) {
  const float* tokens = (const float*)d_in[0];
  const int* leaf_ids = (const int*)d_in[1];
  const int* op_ids = (const int*)d_in[2];
  const float* W0 = (const float*)d_in[3];
  const float* W1 = (const float*)d_in[4];
  const float* W2 = (const float*)d_in[5];
  const float* W3 = (const float*)d_in[6];
  const float* U0 = (const float*)d_in[7];
  const float* U1 = (const float*)d_in[8];
  const float* U2 = (const float*)d_in[9];
  const float* U3 = (const float*)d_in[10];
  const float* B0 = (const float*)d_in[11];
  const float* B1 = (const float*)d_in[12];
  const float* B2 = (const float*)d_in[13];
  const float* B3 = (const float*)d_in[14];
  const float* op_emb = (const float*)d_in[15];
  const float* c_init = (const float*)d_in[16];
  const float* h_init = (const float*)d_in[17];
  float* out = (float*)d_out;

  char* ws = (char*)d_ws;
  u16* Wb = (u16*)ws;
  u16* Ub = Wb + (size_t)4 * 1024 * 1024;
  u16* Xl = Ub + (size_t)4 * 1024 * 1024;
  u16* hA = Xl + (size_t)8192 * 1024;
  u16* hB = hA + (size_t)8192 * 1024;
  float* cA = (float*)(hB + (size_t)4096 * 1024);
  float* cB = cA + (size_t)8192 * 1024;
  float* xw = cB + (size_t)4096 * 1024;
  float* lc = xw + 16 * 1024;

  // fused setup: convert (8192) | gather (8192) | wave-parallel dots (5376)
  setup_kernel<<<21760, 256, 0, stream>>>(tokens, leaf_ids,
                                          W0, W1, W2, W3, U0, U1, U2, U3,
                                          B0, B1, B2, B3, op_emb, h_init,
                                          Wb, Ub, Xl, xw, lc);

  // leaves: 8192 rows -> <8,2>: 64 rowgroups x 32 stripes
  tree_gemm<8, 2><<<64 * 32, 256, 0, stream>>>(Xl, Wb, lc, nullptr, c_init,
                                               cA, hA, 8192, 0, 1, out);

  const u16* hin = hA; const float* cin = cA;
  u16* hout = hB; float* cout = cB;
  for (int l = 12; l >= 0; --l) {
    int m = 1 << l;
    int nrows = 2 * m;
    if (nrows >= 2048) {
      tree_gemm<8, 2><<<(nrows / 128) * 32, 256, 0, stream>>>(
          hin, Ub, xw, op_ids + (m - 1), cin, cout, hout, nrows, m, 0, out);
    } else if (nrows >= 1024) {
      tree_gemm<4, 2><<<(nrows / 64) * 32, 256, 0, stream>>>(
          hin, Ub, xw, op_ids + (m - 1), cin, cout, hout, nrows, m, 0, out);
    } else {
      int rg = nrows / 32; if (rg < 1) rg = 1;
      small_gemm<<<rg * 32, 256, 0, stream>>>(
          hin, Ub, xw, op_ids + (m - 1), cin, cout, hout, nrows, m, out);
    }
    const u16* th = hin; hin = hout; hout = (u16*)th;
    const float* tc = cin; cin = cout; cout = (float*)tc;
  }
}